// Round 1
// baseline (54.825 us; speedup 1.0000x reference)
//
#include <hip/hip_runtime.h>
#include <math.h>

// Problem constants (from reference setup_inputs)
#define CDIM 64
#define CR 16
#define TFR 8
#define NBATCH 16      // NT / T
#define NTOT 128       // NT
#define HWPIX 3136     // 56*56
#define HW4 784        // HWPIX / 4

// ---------------------------------------------------------------------------
// Kernel 1: per-(nt, c) spatial mean of x.  grid = NT*C blocks, 256 threads.
// x layout: (NT, C, H, W) contiguous -> block b reduces x[b*3136 .. +3136)
// ---------------------------------------------------------------------------
__global__ __launch_bounds__(256) void spatial_mean_kernel(
    const float* __restrict__ x, float* __restrict__ xbar) {
  const int b = blockIdx.x;  // 0 .. NT*C-1
  const float4* xp = reinterpret_cast<const float4*>(x + (size_t)b * HWPIX);
  float s = 0.f;
  for (int i = threadIdx.x; i < HW4; i += 256) {
    float4 v = xp[i];
    s += (v.x + v.y) + (v.z + v.w);
  }
  // wave (64-lane) butterfly reduce
  #pragma unroll
  for (int off = 32; off > 0; off >>= 1) s += __shfl_down(s, off, 64);
  __shared__ float wsum[4];
  const int lane = threadIdx.x & 63, wid = threadIdx.x >> 6;
  if (lane == 0) wsum[wid] = s;
  __syncthreads();
  if (threadIdx.x == 0) {
    float tot = (wsum[0] + wsum[1]) + (wsum[2] + wsum[3]);
    xbar[b] = tot * (1.0f / (float)HWPIX);
  }
}

// ---------------------------------------------------------------------------
// Kernel 2 (tiny): att+1 per (nt, c).
// gap[nt,k] = sum_c sq_w[k,c] * (xbar[n,0,c] - xbar[n,t,c])   (0 for t=T-1; sq_b cancels)
// attp1[nt,c] = 1 + sigmoid( sum_k ex_w[c,k]*gap[k] + ex_b[c] )
// grid = NT blocks of C threads.
// ---------------------------------------------------------------------------
__global__ __launch_bounds__(64) void att_kernel(
    const float* __restrict__ xbar,
    const float* __restrict__ sq_w,   // (CR, C) row-major
    const float* __restrict__ ex_w,   // (C, CR) row-major
    const float* __restrict__ ex_b,   // (C,)
    float* __restrict__ attp1) {
  const int nt = blockIdx.x;
  const int n = nt >> 3;           // / TFR
  const int t = nt & 7;            // % TFR
  const int c = threadIdx.x;       // 0..63
  __shared__ float d[CDIM];
  __shared__ float gap[CR];
  d[c] = (t == TFR - 1) ? 0.f
                        : (xbar[(n * TFR) * CDIM + c] - xbar[nt * CDIM + c]);
  __syncthreads();
  if (c < CR) {
    float g = 0.f;
    #pragma unroll
    for (int cc = 0; cc < CDIM; ++cc) g += sq_w[c * CDIM + cc] * d[cc];
    gap[c] = g;
  }
  __syncthreads();
  float a = ex_b[c];
  #pragma unroll
  for (int k = 0; k < CR; ++k) a += ex_w[c * CR + k] * gap[k];
  attp1[nt * CDIM + c] = 1.f + 1.f / (1.f + __expf(-a));
}

// ---------------------------------------------------------------------------
// Kernel 3: fused main pass. Each thread owns one float4 of HW for one (n,c),
// loads x across all 8 frames into registers, computes
//   S = x * attp1
//   Sc = shift-conv(S) (k=3, zero pad)
//   Gc = BN(gate-conv(x))   [BN folded into conv weights]
//   out = Sc * sigmoid(Gc)
// grid = N*C*HW4/256 = 3136 blocks exactly.
// ---------------------------------------------------------------------------
__global__ __launch_bounds__(256) void fused_shift_kernel(
    const float* __restrict__ x,
    const float* __restrict__ attp1,
    const float* __restrict__ shift_w, const float* __restrict__ shift_b,
    const float* __restrict__ gate_w,  const float* __restrict__ gate_b,
    const float* __restrict__ bn_gamma, const float* __restrict__ bn_beta,
    const float* __restrict__ bn_mean,  const float* __restrict__ bn_var,
    float* __restrict__ out) {
  const int tid = blockIdx.x * 256 + threadIdx.x;  // 0 .. 16*64*784-1
  const int q = tid % HW4;
  const int c = (tid / HW4) & (CDIM - 1);
  const int n = tid / (HW4 * CDIM);

  // per-channel constants (L1/L2 broadcast; 784 threads share each c)
  const float sw0 = shift_w[c * 3 + 0], sw1 = shift_w[c * 3 + 1],
              sw2 = shift_w[c * 3 + 2], sb = shift_b[c];
  const float inv = bn_gamma[c] * rsqrtf(bn_var[c] + 1e-3f);
  const float g0 = gate_w[c * 3 + 0] * inv, g1 = gate_w[c * 3 + 1] * inv,
              g2 = gate_w[c * 3 + 2] * inv;
  const float gbias = (gate_b[c] - bn_mean[c]) * inv + bn_beta[c];

  const size_t base = ((size_t)(n * TFR) * CDIM + c) * HWPIX + (size_t)q * 4;
  const size_t tstride = (size_t)CDIM * HWPIX;  // frame stride in floats

  float4 xv[TFR], Sv[TFR];
  #pragma unroll
  for (int t = 0; t < TFR; ++t) {
    xv[t] = *reinterpret_cast<const float4*>(x + base + (size_t)t * tstride);
    const float a = attp1[(n * TFR + t) * CDIM + c];
    Sv[t].x = xv[t].x * a;
    Sv[t].y = xv[t].y * a;
    Sv[t].z = xv[t].z * a;
    Sv[t].w = xv[t].w * a;
  }

  const float4 zero4 = make_float4(0.f, 0.f, 0.f, 0.f);
  #pragma unroll
  for (int t = 0; t < TFR; ++t) {
    const float4 Sm = (t > 0) ? Sv[t - 1] : zero4;
    const float4 Sp = (t < TFR - 1) ? Sv[t + 1] : zero4;
    const float4 xm = (t > 0) ? xv[t - 1] : zero4;
    const float4 xp = (t < TFR - 1) ? xv[t + 1] : zero4;

    float4 o;
    {
      const float sc = sb + sw0 * Sm.x + sw1 * Sv[t].x + sw2 * Sp.x;
      const float gc = gbias + g0 * xm.x + g1 * xv[t].x + g2 * xp.x;
      o.x = sc * (1.f / (1.f + __expf(-gc)));
    }
    {
      const float sc = sb + sw0 * Sm.y + sw1 * Sv[t].y + sw2 * Sp.y;
      const float gc = gbias + g0 * xm.y + g1 * xv[t].y + g2 * xp.y;
      o.y = sc * (1.f / (1.f + __expf(-gc)));
    }
    {
      const float sc = sb + sw0 * Sm.z + sw1 * Sv[t].z + sw2 * Sp.z;
      const float gc = gbias + g0 * xm.z + g1 * xv[t].z + g2 * xp.z;
      o.z = sc * (1.f / (1.f + __expf(-gc)));
    }
    {
      const float sc = sb + sw0 * Sm.w + sw1 * Sv[t].w + sw2 * Sp.w;
      const float gc = gbias + g0 * xm.w + g1 * xv[t].w + g2 * xp.w;
      o.w = sc * (1.f / (1.f + __expf(-gc)));
    }
    *reinterpret_cast<float4*>(out + base + (size_t)t * tstride) = o;
  }
}

extern "C" void kernel_launch(void* const* d_in, const int* in_sizes, int n_in,
                              void* d_out, int out_size, void* d_ws, size_t ws_size,
                              hipStream_t stream) {
  const float* x        = (const float*)d_in[0];
  const float* shift_w  = (const float*)d_in[1];
  const float* shift_b  = (const float*)d_in[2];
  const float* gate_w   = (const float*)d_in[3];
  const float* gate_b   = (const float*)d_in[4];
  const float* bn_gamma = (const float*)d_in[5];
  const float* bn_beta  = (const float*)d_in[6];
  const float* bn_mean  = (const float*)d_in[7];
  const float* bn_var   = (const float*)d_in[8];
  const float* sq_w     = (const float*)d_in[9];
  // d_in[10] = sq_b  (cancels in temporal diff -> unused)
  const float* ex_w     = (const float*)d_in[11];
  const float* ex_b     = (const float*)d_in[12];
  float* out = (float*)d_out;

  float* xbar  = (float*)d_ws;                 // NT*C floats
  float* attp1 = (float*)d_ws + NTOT * CDIM;   // NT*C floats

  spatial_mean_kernel<<<NTOT * CDIM, 256, 0, stream>>>(x, xbar);
  att_kernel<<<NTOT, CDIM, 0, stream>>>(xbar, sq_w, ex_w, ex_b, attp1);
  fused_shift_kernel<<<(NBATCH * CDIM * HW4) / 256, 256, 0, stream>>>(
      x, attp1, shift_w, shift_b, gate_w, gate_b,
      bn_gamma, bn_beta, bn_mean, bn_var, out);
}